// Round 2
// baseline (1395.765 us; speedup 1.0000x reference)
//
#include <hip/hip_runtime.h>
#include <math.h>

#define RNK 10
#define NG  55          // packed lower-triangular 10x10
#define TPB 256
#define TPBU 64         // update_kernel block (1 wave) -> 64 blocks, 4x CU coverage
#define WPC 2           // mask words (32 rows each) per gram chunk -> 64 rows, 1024 blocks
#define ROWS_P 32       // rows per chunk, pass1/pass2
#define ITILE 16        // rows per block in final GEMM

__device__ __forceinline__ constexpr int tri(int a, int b) { return a*(a+1)/2 + b; }

// ---------------- init ----------------
// Ut[r,m]<-U^T, Urow[m,10]<-U, Vc[r,n]<-V, Vrow[n,10]<-V^T, zero Gbuf/tauacc/rhs, alpha
__global__ void init_kernel(const float* __restrict__ Uin, const float* __restrict__ Vin,
                            const float* __restrict__ cptr,
                            float* __restrict__ Ut, float* __restrict__ Vc,
                            float* __restrict__ Urow, float* __restrict__ Vrow,
                            float* __restrict__ Gbuf, float* __restrict__ tauacc,
                            float* __restrict__ rhs, float* __restrict__ alpha,
                            int m, int n, int qmax) {
    int idx = blockIdx.x * TPB + threadIdx.x;
    if (idx == 0) {
        float c  = *cptr;
        float A  = erff(c * 0.70710678118654752f);              // chi2_cdf(c^2, 1)
        float B  = c * 0.79788456080286536f * expf(-0.5f*c*c);
        *alpha = 0.5f*c*c*(1.0f - A) + 0.5f*(A - B);            // chi2_cdf(c^2,3)=A-B
    }
    if (idx < RNK * m) { int k = idx / m, i = idx - k*m; Ut[idx] = Uin[i*RNK + k]; }
    if (idx < RNK * m) Urow[idx] = Uin[idx];                    // same layout
    if (idx < RNK * n) Vc[idx] = Vin[idx];
    if (idx < RNK * n) { int j = idx / RNK, k = idx - j*RNK; Vrow[idx] = Vin[k*n + j]; }
    if (idx < (NG + 1) * qmax) Gbuf[idx] = 0.0f;
    if (idx < qmax) tauacc[idx] = 0.0f;
    if (idx < RNK * qmax) rhs[idx] = 0.0f;
}

// X [m,n] -> XT [n,m], 32x32 LDS tile
__global__ void transpose_kernel(const float* __restrict__ X, float* __restrict__ XT,
                                 int m, int n) {
    __shared__ float tile[32][33];
    int bx = blockIdx.x * 32, by = blockIdx.y * 32;
    int tx = threadIdx.x, ty = threadIdx.y;  // block (32,8)
    #pragma unroll
    for (int dy = 0; dy < 32; dy += 8)
        tile[ty+dy][tx] = X[(size_t)(by+ty+dy)*n + bx + tx];
    __syncthreads();
    #pragma unroll
    for (int dy = 0; dy < 32; dy += 8)
        XT[(size_t)(bx+ty+dy)*m + by + tx] = tile[tx][ty+dy];
}

// Build packed masks. maskV [m/32][n]: bit u of word (w,j) = (X[32w+u, j] != 0).
// maskU [n/32][m]: bit u of word (w,i) = (X[i, 32w+u] != 0)  (via 64-lane ballot).
// grid (n/256, m/32), block 256 = 4 waves; each wave: 64 cols x 32 rows.
__global__ void mask_kernel(const float* __restrict__ X, unsigned* __restrict__ maskV,
                            unsigned* __restrict__ maskU, int m, int n) {
    int wave = threadIdx.x >> 6, lane = threadIdx.x & 63;
    int jbase = blockIdx.x * 256 + wave * 64;
    int j  = jbase + lane;
    int i0 = blockIdx.y * 32;
    unsigned wv = 0;
    for (int u = 0; u < 32; ++u) {
        float x = X[(size_t)(i0+u)*n + j];
        bool nz = (x != 0.0f);
        wv |= (nz ? 1u : 0u) << u;
        unsigned long long bb = __ballot(nz);
        if (lane == 0) {
            int jw = jbase >> 5;
            maskU[(size_t)jw     * m + (i0+u)] = (unsigned)bb;
            maskU[(size_t)(jw+1) * m + (i0+u)] = (unsigned)(bb >> 32);
        }
    }
    maskV[(size_t)blockIdx.y * n + j] = wv;
}

// ---------------- hubreg kernels ----------------
// Gram from packed mask bits only: no Y stream. D rows via wave-uniform s_load
// (round-0 proven body: issue ~= floor). acc[55] lives in AGPRs -- free on gfx950
// (VALU reads AGPRs directly). WPC=2 -> 1024 blocks = 4 blocks/CU = 4 waves/SIMD
// to hide the s_load/atomic latency that left round 0 at 70% idle.
__global__ __launch_bounds__(TPB)
void gram_kernel(const unsigned* __restrict__ mask, const float* __restrict__ Drow,
                 float* __restrict__ Gbuf, int q, int p) {
    int j  = blockIdx.x * TPB + threadIdx.x;
    int w0 = blockIdx.y * WPC;
    unsigned words[WPC];
    #pragma unroll
    for (int w = 0; w < WPC; ++w) words[w] = mask[(size_t)(w0+w)*q + j];
    float acc[NG];
    #pragma unroll
    for (int k = 0; k < NG; ++k) acc[k] = 0.0f;
    unsigned cnt = 0;
    int ib = w0 * 32;
    // prefetch first D row (wave-uniform -> SGPRs)
    float dc[RNK];
    #pragma unroll
    for (int k = 0; k < RNK; ++k) dc[k] = Drow[(size_t)ib*RNK + k];
    #pragma unroll
    for (int w = 0; w < WPC; ++w) {
        unsigned word = words[w];
        cnt += __popc(word);
        for (int u = 0; u < 32; ++u) {
            int inext = ib + w*32 + u + 1;
            if (inext > p - 1) inext = p - 1;
            float dn[RNK];
            #pragma unroll
            for (int k = 0; k < RNK; ++k) dn[k] = Drow[(size_t)inext*RNK + k];
            float f = (float)((word >> u) & 1u);
            #pragma unroll
            for (int a = 0; a < RNK; ++a) {
                float t = f * dc[a];
                #pragma unroll
                for (int b = 0; b <= a; ++b)
                    acc[tri(a,b)] = fmaf(t, dc[b], acc[tri(a,b)]);
            }
            #pragma unroll
            for (int k = 0; k < RNK; ++k) dc[k] = dn[k];
        }
    }
    #pragma unroll
    for (int k = 0; k < NG; ++k) atomicAdd(&Gbuf[k*q + j], acc[k]);
    atomicAdd(&Gbuf[NG*q + j], (float)cnt);
}

// pass1: tauacc[j] += sum_i (clamp(resid, +-c*sig))^2.
// 2 cols/thread (float2 loads, 8B/lane), 8-deep row prefetch.
// use_store=0: sig = *sigma0p (it=0);  use_store=1: sig = sigstore[j] (it=1).
__global__ __launch_bounds__(TPB)
void pass1_kernel(const float* __restrict__ Y, const float* __restrict__ Drow,
                  const float* __restrict__ Bm, const float* __restrict__ sigstore,
                  const float* __restrict__ sigma0p, const float* __restrict__ cptr,
                  float* __restrict__ tauacc, int q, int p, int use_store) {
    int j0 = (blockIdx.x * TPB + threadIdx.x) * 2;
    int i0 = blockIdx.y * ROWS_P;
    float b0[RNK], b1[RNK];
    #pragma unroll
    for (int k = 0; k < RNK; ++k) {
        float2 b2 = *(const float2*)&Bm[k*q + j0];
        b0[k] = b2.x; b1[k] = b2.y;
    }
    float c = *cptr;
    float cs0 = c * (use_store ? sigstore[j0]   : *sigma0p);
    float cs1 = c * (use_store ? sigstore[j0+1] : *sigma0p);
    float a0 = 0.0f, a1 = 0.0f;
    float2 y[8];
    #pragma unroll
    for (int u = 0; u < 8; ++u) y[u] = *(const float2*)&Y[(size_t)(i0+u)*q + j0];
    for (int g = 0; g < ROWS_P; g += 8) {
        float2 yn[8];
        if (g + 8 < ROWS_P) {
            #pragma unroll
            for (int u = 0; u < 8; ++u) yn[u] = *(const float2*)&Y[(size_t)(i0+g+8+u)*q + j0];
        } else {
            #pragma unroll
            for (int u = 0; u < 8; ++u) yn[u] = make_float2(0.0f, 0.0f);
        }
        #pragma unroll
        for (int u = 0; u < 8; ++u) {
            int i = i0 + g + u;
            const float* dd = Drow + (size_t)i*RNK;   // wave-uniform -> s_load
            float dot0 = 0.0f, dot1 = 0.0f;
            #pragma unroll
            for (int k = 0; k < RNK; ++k) {
                float d = dd[k];
                dot0 = fmaf(d, b0[k], dot0);
                dot1 = fmaf(d, b1[k], dot1);
            }
            float r0 = (y[u].x != 0.0f) ? y[u].x - dot0 : 0.0f;
            float r1 = (y[u].y != 0.0f) ? y[u].y - dot1 : 0.0f;
            r0 = fminf(fmaxf(r0, -cs0), cs0);
            r1 = fminf(fmaxf(r1, -cs1), cs1);
            a0 = fmaf(r0, r0, a0);
            a1 = fmaf(r1, r1, a1);
        }
        #pragma unroll
        for (int u = 0; u < 8; ++u) y[u] = yn[u];
    }
    atomicAdd(&tauacc[j0],   a0);
    atomicAdd(&tauacc[j0+1], a1);
}

// pass2: sigma_new inline from tauacc; rhs[k][j] += D[i,k]*clamp(resid,+-c*sigma_new).
// 2 cols/thread (float2). mode 0: sig_old = *sigma0p, chunk-0 stores sigma_new.
// mode 1: sig_old = sigstore[j].
__global__ __launch_bounds__(TPB)
void pass2_kernel(const float* __restrict__ Y, const float* __restrict__ Drow,
                  const float* __restrict__ Bm, const float* __restrict__ Gbuf,
                  const float* __restrict__ tauacc, float* __restrict__ sigstore,
                  const float* __restrict__ cptr, const float* __restrict__ alphap,
                  const float* __restrict__ lamdap, const float* __restrict__ sigma0p,
                  float* __restrict__ rhs, int q, int p, int mode) {
    int j0 = (blockIdx.x * TPB + threadIdx.x) * 2;
    int i0 = blockIdx.y * ROWS_P;
    float b0[RNK], b1[RNK];
    #pragma unroll
    for (int k = 0; k < RNK; ++k) {
        float2 b2 = *(const float2*)&Bm[k*q + j0];
        b0[k] = b2.x; b1[k] = b2.y;
    }
    float c = *cptr, al = *alphap, lam = *lamdap, s0c = *sigma0p;
    float so0 = mode ? sigstore[j0]   : s0c;
    float so1 = mode ? sigstore[j0+1] : s0c;
    float nb0 = Gbuf[NG*q + j0], nb1 = Gbuf[NG*q + j0+1];
    float tau0 = sqrtf(tauacc[j0]   / (2.0f * nb0 * al)) / so0;
    float tau1 = sqrtf(tauacc[j0+1] / (2.0f * nb1 * al)) / so1;
    float sg0 = so0 * powf(tau0, lam);
    float sg1 = so1 * powf(tau1, lam);
    if (mode == 0 && blockIdx.y == 0) { sigstore[j0] = sg0; sigstore[j0+1] = sg1; }
    float cs0 = c * sg0, cs1 = c * sg1;

    float a0[RNK], a1[RNK];
    #pragma unroll
    for (int k = 0; k < RNK; ++k) { a0[k] = 0.0f; a1[k] = 0.0f; }
    float2 y[8];
    #pragma unroll
    for (int u = 0; u < 8; ++u) y[u] = *(const float2*)&Y[(size_t)(i0+u)*q + j0];
    for (int g = 0; g < ROWS_P; g += 8) {
        float2 yn[8];
        if (g + 8 < ROWS_P) {
            #pragma unroll
            for (int u = 0; u < 8; ++u) yn[u] = *(const float2*)&Y[(size_t)(i0+g+8+u)*q + j0];
        } else {
            #pragma unroll
            for (int u = 0; u < 8; ++u) yn[u] = make_float2(0.0f, 0.0f);
        }
        #pragma unroll
        for (int u = 0; u < 8; ++u) {
            int i = i0 + g + u;
            const float* dd = Drow + (size_t)i*RNK;   // wave-uniform -> s_load
            float dot0 = 0.0f, dot1 = 0.0f;
            #pragma unroll
            for (int k = 0; k < RNK; ++k) {
                float d = dd[k];
                dot0 = fmaf(d, b0[k], dot0);
                dot1 = fmaf(d, b1[k], dot1);
            }
            float r0 = (y[u].x != 0.0f) ? y[u].x - dot0 : 0.0f;
            float r1 = (y[u].y != 0.0f) ? y[u].y - dot1 : 0.0f;
            r0 = fminf(fmaxf(r0, -cs0), cs0);   // psi2 * sigma_new
            r1 = fminf(fmaxf(r1, -cs1), cs1);
            #pragma unroll
            for (int k = 0; k < RNK; ++k) {
                float d = dd[k];
                a0[k] = fmaf(d, r0, a0[k]);
                a1[k] = fmaf(d, r1, a1[k]);
            }
        }
        #pragma unroll
        for (int u = 0; u < 8; ++u) y[u] = yn[u];
    }
    #pragma unroll
    for (int k = 0; k < RNK; ++k) {
        atomicAdd(&rhs[k*q + j0],   a0[k]);
        atomicAdd(&rhs[k*q + j0+1], a1[k]);
    }
}

// Cholesky of raw G (in registers) + solve + beta += mu*delta.
// 64-thread blocks -> 64 blocks over 64 CUs (was 16 blocks = 6% of chip).
// Writes BOTH beta layouts (Bm [r,q] and Brow [q,r]). Zeroes tauacc and rhs;
// zero_g also resets Gbuf for the next hubreg call.
__global__ __launch_bounds__(TPBU)
void update_kernel(float* __restrict__ Gbuf, float* __restrict__ rhs,
                   float* __restrict__ Bm, float* __restrict__ Brow,
                   const float* __restrict__ mup,
                   float* __restrict__ tauacc, int q, int zero_g) {
    int j = blockIdx.x * TPBU + threadIdx.x;
    if (j >= q) return;
    float g[NG];
    #pragma unroll
    for (int k = 0; k < NG; ++k) g[k] = Gbuf[k*q + j];
    #pragma unroll
    for (int a = 0; a < RNK; ++a) {          // in-register Cholesky
        #pragma unroll
        for (int b = 0; b < a; ++b) {
            float s = g[tri(a,b)];
            #pragma unroll
            for (int k = 0; k < b; ++k) s -= g[tri(a,k)] * g[tri(b,k)];
            g[tri(a,b)] = s / g[tri(b,b)];
        }
        float s = g[tri(a,a)];
        #pragma unroll
        for (int k = 0; k < a; ++k) s -= g[tri(a,k)] * g[tri(a,k)];
        g[tri(a,a)] = sqrtf(s);
    }
    float x[RNK];
    #pragma unroll
    for (int k = 0; k < RNK; ++k) x[k] = rhs[k*q + j];
    #pragma unroll
    for (int a = 0; a < RNK; ++a) {          // forward: L y = rhs
        float s = x[a];
        #pragma unroll
        for (int k = 0; k < a; ++k) s -= g[tri(a,k)] * x[k];
        x[a] = s / g[tri(a,a)];
    }
    #pragma unroll
    for (int a = RNK-1; a >= 0; --a) {       // backward: L^T d = y
        float s = x[a];
        #pragma unroll
        for (int k = a+1; k < RNK; ++k) s -= g[tri(k,a)] * x[k];
        x[a] = s / g[tri(a,a)];
    }
    float mu = *mup;
    #pragma unroll
    for (int k = 0; k < RNK; ++k) {
        float nb = Bm[k*q + j] + mu * x[k];
        Bm[k*q + j] = nb;
        Brow[(size_t)j*RNK + k] = nb;
    }
    tauacc[j] = 0.0f;
    #pragma unroll
    for (int k = 0; k < RNK; ++k) rhs[k*q + j] = 0.0f;
    if (zero_g) {
        #pragma unroll
        for (int k = 0; k <= NG; ++k) Gbuf[k*q + j] = 0.0f;
    }
}

// final: out[i*n+j..j+3] = sum_k Ut[k*m+i] * Vc[k*n+j..j+3]  (float4 loads/stores)
__global__ void gemm_kernel(const float* __restrict__ Ut, const float* __restrict__ Vc,
                            float* __restrict__ out, int m, int n) {
    int j  = (blockIdx.x * TPB + threadIdx.x) * 4;
    int i0 = blockIdx.y * ITILE;
    float4 v[RNK];
    #pragma unroll
    for (int k = 0; k < RNK; ++k) v[k] = *(const float4*)&Vc[k*n + j];
    #pragma unroll 4
    for (int i = i0; i < i0 + ITILE; ++i) {
        float4 acc = make_float4(0.f, 0.f, 0.f, 0.f);
        #pragma unroll
        for (int k = 0; k < RNK; ++k) {
            float u = Ut[k*m + i];            // wave-uniform -> s_load
            acc.x = fmaf(u, v[k].x, acc.x);
            acc.y = fmaf(u, v[k].y, acc.y);
            acc.z = fmaf(u, v[k].z, acc.z);
            acc.w = fmaf(u, v[k].w, acc.w);
        }
        *(float4*)&out[(size_t)i*n + j] = acc;
    }
}

// ---------------- host side ----------------

namespace {
struct Scratch {
    float *Ut, *Vc, *Urow, *Vrow, *Gbuf, *rhs, *sigma, *tauacc, *alpha;
    unsigned *maskV, *maskU;
};

static void hubreg(const float* Y, const unsigned* mask, const float* Drow,
                   float* Bm, float* Brow, int q, int p,
                   const float* c, const float* lamda, const float* mu, const float* sigma0,
                   const Scratch& s, hipStream_t stream) {
    dim3 gg(q / TPB, p / (32 * WPC));        // gram: 1024 blocks
    dim3 gp(q / (TPB * 2), p / ROWS_P);      // pass kernels (2 cols/thread)
    dim3 gj(q / TPBU);                       // per-regression kernels: 64 blocks

    gram_kernel  <<<gg, TPB, 0, stream>>>(mask, Drow, s.Gbuf, q, p);
    pass1_kernel <<<gp, TPB, 0, stream>>>(Y, Drow, Bm, s.sigma, sigma0, c, s.tauacc, q, p, 0);
    pass2_kernel <<<gp, TPB, 0, stream>>>(Y, Drow, Bm, s.Gbuf, s.tauacc, s.sigma, c,
                                          s.alpha, lamda, sigma0, s.rhs, q, p, 0);
    update_kernel<<<gj, TPBU, 0, stream>>>(s.Gbuf, s.rhs, Bm, Brow, mu, s.tauacc, q, 0);
    pass1_kernel <<<gp, TPB, 0, stream>>>(Y, Drow, Bm, s.sigma, sigma0, c, s.tauacc, q, p, 1);
    pass2_kernel <<<gp, TPB, 0, stream>>>(Y, Drow, Bm, s.Gbuf, s.tauacc, s.sigma, c,
                                          s.alpha, lamda, sigma0, s.rhs, q, p, 1);
    update_kernel<<<gj, TPBU, 0, stream>>>(s.Gbuf, s.rhs, Bm, Brow, mu, s.tauacc, q, 1);
}
} // namespace

extern "C" void kernel_launch(void* const* d_in, const int* in_sizes, int n_in,
                              void* d_out, int out_size, void* d_ws, size_t ws_size,
                              hipStream_t stream) {
    const float* Uin    = (const float*)d_in[0];
    const float* Vin    = (const float*)d_in[1];
    const float* X      = (const float*)d_in[2];
    const float* c      = (const float*)d_in[3];
    const float* lamda  = (const float*)d_in[4];
    const float* mu     = (const float*)d_in[5];
    const float* sigma0 = (const float*)d_in[6];
    float* out = (float*)d_out;

    const int m = in_sizes[0] / RNK;   // 4096
    const int n = in_sizes[1] / RNK;   // 4096
    const int qmax = (m > n) ? m : n;

    float* w = (float*)d_ws;
    auto align64 = [](size_t x) { return (x + 63) & ~(size_t)63; };
    size_t off = 0;
    Scratch s;
    s.Ut     = w + off; off = align64(off + (size_t)RNK * m);
    s.Vc     = w + off; off = align64(off + (size_t)RNK * n);
    s.Urow   = w + off; off = align64(off + (size_t)RNK * m);
    s.Vrow   = w + off; off = align64(off + (size_t)RNK * n);
    s.Gbuf   = w + off; off = align64(off + (size_t)(NG + 1) * qmax);
    s.rhs    = w + off; off = align64(off + (size_t)RNK * qmax);
    s.sigma  = w + off; off = align64(off + (size_t)qmax);
    s.tauacc = w + off; off = align64(off + (size_t)qmax);
    s.alpha  = w + off; off = align64(off + 64);
    s.maskV  = (unsigned*)(w + off); off = align64(off + (size_t)(m/32) * n);
    s.maskU  = (unsigned*)(w + off); off = align64(off + (size_t)(n/32) * m);
    (void)ws_size; (void)n_in; (void)out_size;

    {
        int tot = (NG + 1) * qmax;
        init_kernel<<<(tot + TPB - 1) / TPB, TPB, 0, stream>>>(
            Uin, Vin, c, s.Ut, s.Vc, s.Urow, s.Vrow, s.Gbuf, s.tauacc, s.rhs,
            s.alpha, m, n, qmax);
    }
    // X [m,n] -> XT [n,m] staged in d_out (dead until final GEMM overwrites it)
    transpose_kernel<<<dim3(n / 32, m / 32), dim3(32, 8), 0, stream>>>(X, out, m, n);
    mask_kernel<<<dim3(n / 256, m / 32), TPB, 0, stream>>>(X, s.maskV, s.maskU, m, n);

    for (int layer = 0; layer < 3; ++layer) {
        // V-step: q=n regressions (cols of X), D rows = U rows (Urow), beta = V cols
        hubreg(X,   s.maskV, s.Urow, s.Vc, s.Vrow, n, m, c, lamda, mu, sigma0, s, stream);
        // U-step: q=m regressions (rows of X), Y = XT, D rows = V cols (Vrow), beta = U rows
        hubreg(out, s.maskU, s.Vrow, s.Ut, s.Urow, m, n, c, lamda, mu, sigma0, s, stream);
    }

    gemm_kernel<<<dim3(n / (TPB * 4), m / ITILE), TPB, 0, stream>>>(s.Ut, s.Vc, out, m, n);
}

// Round 3
// 1168.948 us; speedup vs baseline: 1.1940x; 1.1940x over previous
//
#include <hip/hip_runtime.h>
#include <math.h>

#define RNK 10
#define NG  55          // packed lower-triangular 10x10
#define TPB 256
#define WPC 4           // mask words (32 rows each) per gram chunk -> 128 rows
#define ROWS_P 32       // rows per chunk, pass1/pass2
#define ITILE 16        // rows per block in final GEMM

__device__ __forceinline__ constexpr int tri(int a, int b) { return a*(a+1)/2 + b; }

// ---------------- init ----------------
// Ut[r,m]<-U^T, Urow[m,10]<-U, Vc[r,n]<-V, Vrow[n,10]<-V^T, zero Gbuf/tauacc/rhs, alpha
__global__ void init_kernel(const float* __restrict__ Uin, const float* __restrict__ Vin,
                            const float* __restrict__ cptr,
                            float* __restrict__ Ut, float* __restrict__ Vc,
                            float* __restrict__ Urow, float* __restrict__ Vrow,
                            float* __restrict__ Gbuf, float* __restrict__ tauacc,
                            float* __restrict__ rhs, float* __restrict__ alpha,
                            int m, int n, int qmax) {
    int idx = blockIdx.x * TPB + threadIdx.x;
    if (idx == 0) {
        float c  = *cptr;
        float A  = erff(c * 0.70710678118654752f);              // chi2_cdf(c^2, 1)
        float B  = c * 0.79788456080286536f * expf(-0.5f*c*c);
        *alpha = 0.5f*c*c*(1.0f - A) + 0.5f*(A - B);            // chi2_cdf(c^2,3)=A-B
    }
    if (idx < RNK * m) { int k = idx / m, i = idx - k*m; Ut[idx] = Uin[i*RNK + k]; }
    if (idx < RNK * m) Urow[idx] = Uin[idx];                    // same layout
    if (idx < RNK * n) Vc[idx] = Vin[idx];
    if (idx < RNK * n) { int j = idx / RNK, k = idx - j*RNK; Vrow[idx] = Vin[k*n + j]; }
    if (idx < (NG + 1) * qmax) Gbuf[idx] = 0.0f;
    if (idx < qmax) tauacc[idx] = 0.0f;
    if (idx < RNK * qmax) rhs[idx] = 0.0f;
}

// X [m,n] -> XT [n,m], 32x32 LDS tile
__global__ void transpose_kernel(const float* __restrict__ X, float* __restrict__ XT,
                                 int m, int n) {
    __shared__ float tile[32][33];
    int bx = blockIdx.x * 32, by = blockIdx.y * 32;
    int tx = threadIdx.x, ty = threadIdx.y;  // block (32,8)
    #pragma unroll
    for (int dy = 0; dy < 32; dy += 8)
        tile[ty+dy][tx] = X[(size_t)(by+ty+dy)*n + bx + tx];
    __syncthreads();
    #pragma unroll
    for (int dy = 0; dy < 32; dy += 8)
        XT[(size_t)(bx+ty+dy)*m + by + tx] = tile[tx][ty+dy];
}

// Build packed masks. maskV [m/32][n]: bit u of word (w,j) = (X[32w+u, j] != 0).
// maskU [n/32][m]: bit u of word (w,i) = (X[i, 32w+u] != 0)  (via 64-lane ballot).
// grid (n/256, m/32), block 256 = 4 waves; each wave: 64 cols x 32 rows.
__global__ void mask_kernel(const float* __restrict__ X, unsigned* __restrict__ maskV,
                            unsigned* __restrict__ maskU, int m, int n) {
    int wave = threadIdx.x >> 6, lane = threadIdx.x & 63;
    int jbase = blockIdx.x * 256 + wave * 64;
    int j  = jbase + lane;
    int i0 = blockIdx.y * 32;
    unsigned wv = 0;
    for (int u = 0; u < 32; ++u) {
        float x = X[(size_t)(i0+u)*n + j];
        bool nz = (x != 0.0f);
        wv |= (nz ? 1u : 0u) << u;
        unsigned long long bb = __ballot(nz);
        if (lane == 0) {
            int jw = jbase >> 5;
            maskU[(size_t)jw     * m + (i0+u)] = (unsigned)bb;
            maskU[(size_t)(jw+1) * m + (i0+u)] = (unsigned)(bb >> 32);
        }
    }
    maskV[(size_t)blockIdx.y * n + j] = wv;
}

// ---------------- hubreg kernels ----------------
// Gram from packed mask bits only: no Y stream. D chunk (128 rows x 48 B, padded)
// staged once in LDS; inner 32-row loop FULLY unrolled so every row read is
// ds_read_b128/b64 at a compile-time immediate offset (zero address VALU,
// broadcast = conflict-free). 65 FMAs/row hit distinct acc entries -> fully
// independent, single wave sustains near-full VALU issue. Next mask word
// prefetched above ~4500 cy of straight-line VALU. VALU floor = 16.6 us.
__global__ __launch_bounds__(TPB)
void gram_kernel(const unsigned* __restrict__ mask, const float* __restrict__ Drow,
                 float* __restrict__ Gbuf, int q, int p) {
    __shared__ __align__(16) float Dld[WPC * 32][12];   // 128 rows x 48 B = 6 KB
    int j  = blockIdx.x * TPB + threadIdx.x;
    int w0 = blockIdx.y * WPC;
    int ib = w0 * 32;
    #pragma unroll
    for (int t = threadIdx.x; t < WPC * 32 * RNK; t += TPB) {   // 5 coalesced iters
        int row = t / RNK, k = t - row * RNK;
        Dld[row][k] = Drow[(size_t)ib * RNK + t];
    }
    __syncthreads();
    float acc[NG];
    #pragma unroll
    for (int k = 0; k < NG; ++k) acc[k] = 0.0f;
    unsigned cnt = 0;
    unsigned wnext = mask[(size_t)w0 * q + j];
    for (int w = 0; w < WPC; ++w) {          // rolled: keeps body ~18 KB (I-cache)
        unsigned word = wnext;
        int wn = (w + 1 < WPC) ? (w + 1) : (WPC - 1);
        wnext = mask[(size_t)(w0 + wn) * q + j];   // hidden under the FMA block
        cnt += __popc(word);
        #pragma unroll
        for (int u = 0; u < 32; ++u) {       // fully unrolled: imm-offset ds_reads
            float f = (float)((word >> u) & 1u);
            float d[RNK];
            #pragma unroll
            for (int k = 0; k < RNK; ++k) d[k] = Dld[w * 32 + u][k];
            #pragma unroll
            for (int a = 0; a < RNK; ++a) {
                float t = f * d[a];
                #pragma unroll
                for (int b = 0; b <= a; ++b)
                    acc[tri(a, b)] = fmaf(t, d[b], acc[tri(a, b)]);
            }
        }
    }
    #pragma unroll
    for (int k = 0; k < NG; ++k) atomicAdd(&Gbuf[k * q + j], acc[k]);
    atomicAdd(&Gbuf[NG * q + j], (float)cnt);
}

// pass1: tauacc[j] += sum_i (clamp(resid, +-c*sig))^2. 1 col/thread, 8-deep prefetch.
// use_store=0: sig = *sigma0p (it=0);  use_store=1: sig = sigstore[j] (it=1).
__global__ __launch_bounds__(TPB)
void pass1_kernel(const float* __restrict__ Y, const float* __restrict__ Drow,
                  const float* __restrict__ Bm, const float* __restrict__ sigstore,
                  const float* __restrict__ sigma0p, const float* __restrict__ cptr,
                  float* __restrict__ tauacc, int q, int p, int use_store) {
    int j  = blockIdx.x * TPB + threadIdx.x;
    int i0 = blockIdx.y * ROWS_P;
    float b[RNK];
    #pragma unroll
    for (int k = 0; k < RNK; ++k) b[k] = Bm[k*q + j];
    float csg = (*cptr) * (use_store ? sigstore[j] : *sigma0p);
    float a0 = 0.0f;
    float y[8];
    #pragma unroll
    for (int u = 0; u < 8; ++u) y[u] = Y[(size_t)(i0+u)*q + j];
    for (int g = 0; g < ROWS_P; g += 8) {
        float yn[8];
        if (g + 8 < ROWS_P) {
            #pragma unroll
            for (int u = 0; u < 8; ++u) yn[u] = Y[(size_t)(i0+g+8+u)*q + j];
        } else {
            #pragma unroll
            for (int u = 0; u < 8; ++u) yn[u] = 0.0f;
        }
        #pragma unroll
        for (int u = 0; u < 8; ++u) {
            int i = i0 + g + u;
            const float* dd = Drow + (size_t)i*RNK;   // wave-uniform -> s_load
            float dot = 0.0f;
            #pragma unroll
            for (int k = 0; k < RNK; ++k) dot = fmaf(dd[k], b[k], dot);
            float r = (y[u] != 0.0f) ? y[u] - dot : 0.0f;
            r = fminf(fmaxf(r, -csg), csg);
            a0 = fmaf(r, r, a0);
        }
        #pragma unroll
        for (int u = 0; u < 8; ++u) y[u] = yn[u];
    }
    atomicAdd(&tauacc[j], a0);
}

// pass2: sigma_new inline from tauacc; rhs[k][j] += D[i,k]*clamp(resid,+-c*sigma_new).
// mode 0: sig_old = *sigma0p, chunk-0 stores sigma_new. mode 1: sig_old = sigstore[j].
__global__ __launch_bounds__(TPB)
void pass2_kernel(const float* __restrict__ Y, const float* __restrict__ Drow,
                  const float* __restrict__ Bm, const float* __restrict__ Gbuf,
                  const float* __restrict__ tauacc, float* __restrict__ sigstore,
                  const float* __restrict__ cptr, const float* __restrict__ alphap,
                  const float* __restrict__ lamdap, const float* __restrict__ sigma0p,
                  float* __restrict__ rhs, int q, int p, int mode) {
    int j  = blockIdx.x * TPB + threadIdx.x;
    int i0 = blockIdx.y * ROWS_P;
    float b[RNK];
    #pragma unroll
    for (int k = 0; k < RNK; ++k) b[k] = Bm[k*q + j];
    float so  = mode ? sigstore[j] : *sigma0p;
    float nb  = Gbuf[NG*q + j];
    float tau = sqrtf(tauacc[j] / (2.0f * nb * (*alphap))) / so;
    float sg  = so * powf(tau, *lamdap);
    if (mode == 0 && blockIdx.y == 0) sigstore[j] = sg;
    float csg = (*cptr) * sg;

    float a[RNK];
    #pragma unroll
    for (int k = 0; k < RNK; ++k) a[k] = 0.0f;
    float y[8];
    #pragma unroll
    for (int u = 0; u < 8; ++u) y[u] = Y[(size_t)(i0+u)*q + j];
    for (int g = 0; g < ROWS_P; g += 8) {
        float yn[8];
        if (g + 8 < ROWS_P) {
            #pragma unroll
            for (int u = 0; u < 8; ++u) yn[u] = Y[(size_t)(i0+g+8+u)*q + j];
        } else {
            #pragma unroll
            for (int u = 0; u < 8; ++u) yn[u] = 0.0f;
        }
        #pragma unroll
        for (int u = 0; u < 8; ++u) {
            int i = i0 + g + u;
            const float* dd = Drow + (size_t)i*RNK;   // wave-uniform -> s_load
            float dot = 0.0f;
            #pragma unroll
            for (int k = 0; k < RNK; ++k) dot = fmaf(dd[k], b[k], dot);
            float r = (y[u] != 0.0f) ? y[u] - dot : 0.0f;
            r = fminf(fmaxf(r, -csg), csg);   // psi2 * sigma_new
            #pragma unroll
            for (int k = 0; k < RNK; ++k) a[k] = fmaf(dd[k], r, a[k]);
        }
        #pragma unroll
        for (int u = 0; u < 8; ++u) y[u] = yn[u];
    }
    #pragma unroll
    for (int k = 0; k < RNK; ++k) atomicAdd(&rhs[k*q + j], a[k]);
}

// Cholesky of raw G (in registers) + solve + beta += mu*delta.
// Writes BOTH beta layouts (Bm [r,q] and Brow [q,r]). Zeroes tauacc and rhs;
// zero_g also resets Gbuf for the next hubreg call.
__global__ void update_kernel(float* __restrict__ Gbuf, float* __restrict__ rhs,
                              float* __restrict__ Bm, float* __restrict__ Brow,
                              const float* __restrict__ mup,
                              float* __restrict__ tauacc, int q, int zero_g) {
    int j = blockIdx.x * TPB + threadIdx.x;
    if (j >= q) return;
    float g[NG];
    #pragma unroll
    for (int k = 0; k < NG; ++k) g[k] = Gbuf[k*q + j];
    #pragma unroll
    for (int a = 0; a < RNK; ++a) {          // in-register Cholesky
        #pragma unroll
        for (int b = 0; b < a; ++b) {
            float s = g[tri(a,b)];
            #pragma unroll
            for (int k = 0; k < b; ++k) s -= g[tri(a,k)] * g[tri(b,k)];
            g[tri(a,b)] = s / g[tri(b,b)];
        }
        float s = g[tri(a,a)];
        #pragma unroll
        for (int k = 0; k < a; ++k) s -= g[tri(a,k)] * g[tri(a,k)];
        g[tri(a,a)] = sqrtf(s);
    }
    float x[RNK];
    #pragma unroll
    for (int k = 0; k < RNK; ++k) x[k] = rhs[k*q + j];
    #pragma unroll
    for (int a = 0; a < RNK; ++a) {          // forward: L y = rhs
        float s = x[a];
        #pragma unroll
        for (int k = 0; k < a; ++k) s -= g[tri(a,k)] * x[k];
        x[a] = s / g[tri(a,a)];
    }
    #pragma unroll
    for (int a = RNK-1; a >= 0; --a) {       // backward: L^T d = y
        float s = x[a];
        #pragma unroll
        for (int k = a+1; k < RNK; ++k) s -= g[tri(k,a)] * x[k];
        x[a] = s / g[tri(a,a)];
    }
    float mu = *mup;
    #pragma unroll
    for (int k = 0; k < RNK; ++k) {
        float nb = Bm[k*q + j] + mu * x[k];
        Bm[k*q + j] = nb;
        Brow[(size_t)j*RNK + k] = nb;
    }
    tauacc[j] = 0.0f;
    #pragma unroll
    for (int k = 0; k < RNK; ++k) rhs[k*q + j] = 0.0f;
    if (zero_g) {
        #pragma unroll
        for (int k = 0; k <= NG; ++k) Gbuf[k*q + j] = 0.0f;
    }
}

// final: out[i*n+j] = sum_k Ut[k*m+i] * Vc[k*n+j]
__global__ void gemm_kernel(const float* __restrict__ Ut, const float* __restrict__ Vc,
                            float* __restrict__ out, int m, int n) {
    int j  = blockIdx.x * TPB + threadIdx.x;
    int i0 = blockIdx.y * ITILE;
    float v[RNK];
    #pragma unroll
    for (int k = 0; k < RNK; ++k) v[k] = Vc[k*n + j];
    for (int i = i0; i < i0 + ITILE; ++i) {
        float acc = 0.0f;
        #pragma unroll
        for (int k = 0; k < RNK; ++k) acc = fmaf(Ut[k*m + i], v[k], acc);
        out[(size_t)i*n + j] = acc;
    }
}

// ---------------- host side ----------------

namespace {
struct Scratch {
    float *Ut, *Vc, *Urow, *Vrow, *Gbuf, *rhs, *sigma, *tauacc, *alpha;
    unsigned *maskV, *maskU;
};

static void hubreg(const float* Y, const unsigned* mask, const float* Drow,
                   float* Bm, float* Brow, int q, int p,
                   const float* c, const float* lamda, const float* mu, const float* sigma0,
                   const Scratch& s, hipStream_t stream) {
    dim3 gg(q / TPB, p / (32 * WPC));    // gram
    dim3 gp(q / TPB, p / ROWS_P);        // pass kernels (1 col/thread)
    dim3 gj(q / TPB);                    // per-regression kernels

    gram_kernel  <<<gg, TPB, 0, stream>>>(mask, Drow, s.Gbuf, q, p);
    pass1_kernel <<<gp, TPB, 0, stream>>>(Y, Drow, Bm, s.sigma, sigma0, c, s.tauacc, q, p, 0);
    pass2_kernel <<<gp, TPB, 0, stream>>>(Y, Drow, Bm, s.Gbuf, s.tauacc, s.sigma, c,
                                          s.alpha, lamda, sigma0, s.rhs, q, p, 0);
    update_kernel<<<gj, TPB, 0, stream>>>(s.Gbuf, s.rhs, Bm, Brow, mu, s.tauacc, q, 0);
    pass1_kernel <<<gp, TPB, 0, stream>>>(Y, Drow, Bm, s.sigma, sigma0, c, s.tauacc, q, p, 1);
    pass2_kernel <<<gp, TPB, 0, stream>>>(Y, Drow, Bm, s.Gbuf, s.tauacc, s.sigma, c,
                                          s.alpha, lamda, sigma0, s.rhs, q, p, 1);
    update_kernel<<<gj, TPB, 0, stream>>>(s.Gbuf, s.rhs, Bm, Brow, mu, s.tauacc, q, 1);
}
} // namespace

extern "C" void kernel_launch(void* const* d_in, const int* in_sizes, int n_in,
                              void* d_out, int out_size, void* d_ws, size_t ws_size,
                              hipStream_t stream) {
    const float* Uin    = (const float*)d_in[0];
    const float* Vin    = (const float*)d_in[1];
    const float* X      = (const float*)d_in[2];
    const float* c      = (const float*)d_in[3];
    const float* lamda  = (const float*)d_in[4];
    const float* mu     = (const float*)d_in[5];
    const float* sigma0 = (const float*)d_in[6];
    float* out = (float*)d_out;

    const int m = in_sizes[0] / RNK;   // 4096
    const int n = in_sizes[1] / RNK;   // 4096
    const int qmax = (m > n) ? m : n;

    float* w = (float*)d_ws;
    auto align64 = [](size_t x) { return (x + 63) & ~(size_t)63; };
    size_t off = 0;
    Scratch s;
    s.Ut     = w + off; off = align64(off + (size_t)RNK * m);
    s.Vc     = w + off; off = align64(off + (size_t)RNK * n);
    s.Urow   = w + off; off = align64(off + (size_t)RNK * m);
    s.Vrow   = w + off; off = align64(off + (size_t)RNK * n);
    s.Gbuf   = w + off; off = align64(off + (size_t)(NG + 1) * qmax);
    s.rhs    = w + off; off = align64(off + (size_t)RNK * qmax);
    s.sigma  = w + off; off = align64(off + (size_t)qmax);
    s.tauacc = w + off; off = align64(off + (size_t)qmax);
    s.alpha  = w + off; off = align64(off + 64);
    s.maskV  = (unsigned*)(w + off); off = align64(off + (size_t)(m/32) * n);
    s.maskU  = (unsigned*)(w + off); off = align64(off + (size_t)(n/32) * m);
    (void)ws_size; (void)n_in; (void)out_size;

    {
        int tot = (NG + 1) * qmax;
        init_kernel<<<(tot + TPB - 1) / TPB, TPB, 0, stream>>>(
            Uin, Vin, c, s.Ut, s.Vc, s.Urow, s.Vrow, s.Gbuf, s.tauacc, s.rhs,
            s.alpha, m, n, qmax);
    }
    // X [m,n] -> XT [n,m] staged in d_out (dead until final GEMM overwrites it)
    transpose_kernel<<<dim3(n / 32, m / 32), dim3(32, 8), 0, stream>>>(X, out, m, n);
    mask_kernel<<<dim3(n / 256, m / 32), TPB, 0, stream>>>(X, s.maskV, s.maskU, m, n);

    for (int layer = 0; layer < 3; ++layer) {
        // V-step: q=n regressions (cols of X), D rows = U rows (Urow), beta = V cols
        hubreg(X,   s.maskV, s.Urow, s.Vc, s.Vrow, n, m, c, lamda, mu, sigma0, s, stream);
        // U-step: q=m regressions (rows of X), Y = XT, D rows = V cols (Vrow), beta = U rows
        hubreg(out, s.maskU, s.Vrow, s.Ut, s.Urow, m, n, c, lamda, mu, sigma0, s, stream);
    }

    gemm_kernel<<<dim3(n / TPB, m / ITILE), TPB, 0, stream>>>(s.Ut, s.Vc, out, m, n);
}

// Round 4
// 938.137 us; speedup vs baseline: 1.4878x; 1.2460x over previous
//
#include <hip/hip_runtime.h>
#include <math.h>

#define RNK 10
#define NG  55          // packed lower-triangular 10x10
#define TPB 256
#define TPBU 64         // update block: 1 wave, VGPR cap lifted -> no Cholesky spill
#define WPC 4           // mask words (32 rows each) per gram chunk -> 128 rows
#define ROWS_P 64       // rows per chunk, pass1/pass2 (LDS-staged D)
#define ITILE 16        // rows per block in final GEMM

typedef float f2 __attribute__((ext_vector_type(2)));

__device__ __forceinline__ constexpr int tri(int a, int b) { return a*(a+1)/2 + b; }
// pair-accumulator base index per triangle row a (25 f2 pairs total)
constexpr int BASE2[10] = {0,0,1,2,4,6,9,12,16,20};

// ---------------- init ----------------
__global__ void init_kernel(const float* __restrict__ Uin, const float* __restrict__ Vin,
                            const float* __restrict__ cptr,
                            float* __restrict__ Ut, float* __restrict__ Vc,
                            float* __restrict__ Urow, float* __restrict__ Vrow,
                            float* __restrict__ Gbuf, float* __restrict__ tauacc,
                            float* __restrict__ rhs, float* __restrict__ alpha,
                            int m, int n, int qmax) {
    int idx = blockIdx.x * TPB + threadIdx.x;
    if (idx == 0) {
        float c  = *cptr;
        float A  = erff(c * 0.70710678118654752f);              // chi2_cdf(c^2, 1)
        float B  = c * 0.79788456080286536f * expf(-0.5f*c*c);
        *alpha = 0.5f*c*c*(1.0f - A) + 0.5f*(A - B);            // chi2_cdf(c^2,3)=A-B
    }
    if (idx < RNK * m) { int k = idx / m, i = idx - k*m; Ut[idx] = Uin[i*RNK + k]; }
    if (idx < RNK * m) Urow[idx] = Uin[idx];                    // same layout
    if (idx < RNK * n) Vc[idx] = Vin[idx];
    if (idx < RNK * n) { int j = idx / RNK, k = idx - j*RNK; Vrow[idx] = Vin[k*n + j]; }
    if (idx < (NG + 1) * qmax) Gbuf[idx] = 0.0f;
    if (idx < qmax) tauacc[idx] = 0.0f;
    if (idx < RNK * qmax) rhs[idx] = 0.0f;
}

// X [m,n] -> XT [n,m], 32x32 LDS tile
__global__ void transpose_kernel(const float* __restrict__ X, float* __restrict__ XT,
                                 int m, int n) {
    __shared__ float tile[32][33];
    int bx = blockIdx.x * 32, by = blockIdx.y * 32;
    int tx = threadIdx.x, ty = threadIdx.y;  // block (32,8)
    #pragma unroll
    for (int dy = 0; dy < 32; dy += 8)
        tile[ty+dy][tx] = X[(size_t)(by+ty+dy)*n + bx + tx];
    __syncthreads();
    #pragma unroll
    for (int dy = 0; dy < 32; dy += 8)
        XT[(size_t)(bx+ty+dy)*m + by + tx] = tile[tx][ty+dy];
}

// Build packed masks (see round-0 comments).
__global__ void mask_kernel(const float* __restrict__ X, unsigned* __restrict__ maskV,
                            unsigned* __restrict__ maskU, int m, int n) {
    int wave = threadIdx.x >> 6, lane = threadIdx.x & 63;
    int jbase = blockIdx.x * 256 + wave * 64;
    int j  = jbase + lane;
    int i0 = blockIdx.y * 32;
    unsigned wv = 0;
    for (int u = 0; u < 32; ++u) {
        float x = X[(size_t)(i0+u)*n + j];
        bool nz = (x != 0.0f);
        wv |= (nz ? 1u : 0u) << u;
        unsigned long long bb = __ballot(nz);
        if (lane == 0) {
            int jw = jbase >> 5;
            maskU[(size_t)jw     * m + (i0+u)] = (unsigned)bb;
            maskU[(size_t)(jw+1) * m + (i0+u)] = (unsigned)(bb >> 32);
        }
    }
    maskV[(size_t)blockIdx.y * n + j] = wv;
}

// ---------------- hubreg kernels ----------------
// Gram: LDS-staged D, fully-unrolled rows (round-3 win) + packed-FP32 FMA
// (v_pk_fma_f32 via __builtin_elementwise_fma on float2): 55 FMA + 10 mul ->
// 25 pk_fma + 5 fma + 10 mul = ~40 VALU/row (was 65).
__global__ __launch_bounds__(TPB)
void gram_kernel(const unsigned* __restrict__ mask, const float* __restrict__ Drow,
                 float* __restrict__ Gbuf, int q, int p) {
    __shared__ __align__(16) float Dld[WPC * 32][12];   // 128 rows x 48 B = 6 KB
    int j  = blockIdx.x * TPB + threadIdx.x;
    int w0 = blockIdx.y * WPC;
    int ib = w0 * 32;
    #pragma unroll
    for (int t = threadIdx.x; t < WPC * 32 * RNK; t += TPB) {   // 5 coalesced iters
        int row = t / RNK, k = t - row * RNK;
        Dld[row][k] = Drow[(size_t)ib * RNK + t];
    }
    __syncthreads();
    f2 acc2[25];                 // row a: pairs (b,b+1); even a leaves scalar b=a
    float accs[5];
    #pragma unroll
    for (int k = 0; k < 25; ++k) acc2[k] = (f2){0.0f, 0.0f};
    #pragma unroll
    for (int k = 0; k < 5; ++k) accs[k] = 0.0f;
    unsigned cnt = 0;
    unsigned wnext = mask[(size_t)w0 * q + j];
    for (int w = 0; w < WPC; ++w) {          // rolled: I-cache
        unsigned word = wnext;
        int wn = (w + 1 < WPC) ? (w + 1) : (WPC - 1);
        wnext = mask[(size_t)(w0 + wn) * q + j];   // hidden under the FMA block
        cnt += __popc(word);
        #pragma unroll
        for (int u = 0; u < 32; ++u) {       // fully unrolled: imm-offset ds_reads
            float f = (float)((word >> u) & 1u);
            f2 d2[5];
            #pragma unroll
            for (int k = 0; k < 5; ++k) d2[k] = *(const f2*)&Dld[w * 32 + u][2 * k];
            #pragma unroll
            for (int a = 0; a < RNK; ++a) {
                float da = d2[a >> 1][a & 1];
                float t  = f * da;
                f2 tv = {t, t};
                #pragma unroll
                for (int pb = 0; pb < (a + 1) / 2; ++pb)
                    acc2[BASE2[a] + pb] =
                        __builtin_elementwise_fma(tv, d2[pb], acc2[BASE2[a] + pb]);
                if ((a & 1) == 0) accs[a >> 1] = fmaf(t, da, accs[a >> 1]);
            }
        }
    }
    #pragma unroll
    for (int a = 0; a < RNK; ++a) {
        #pragma unroll
        for (int pb = 0; pb < (a + 1) / 2; ++pb) {
            atomicAdd(&Gbuf[tri(a, 2*pb)   * q + j], acc2[BASE2[a] + pb][0]);
            atomicAdd(&Gbuf[tri(a, 2*pb+1) * q + j], acc2[BASE2[a] + pb][1]);
        }
        if ((a & 1) == 0) atomicAdd(&Gbuf[tri(a, a) * q + j], accs[a >> 1]);
    }
    atomicAdd(&Gbuf[NG * q + j], (float)cnt);
}

// pass1: tauacc[j] += sum_i (clamp(resid, +-c*sig))^2. 1 col/thread, 8-deep Y
// prefetch, D chunk LDS-staged (kills the per-row s_load lgkm stall chain),
// dot via 5 v_pk_fma_f32 + 1 add.
__global__ __launch_bounds__(TPB)
void pass1_kernel(const float* __restrict__ Y, const float* __restrict__ Drow,
                  const float* __restrict__ Bm, const float* __restrict__ sigstore,
                  const float* __restrict__ sigma0p, const float* __restrict__ cptr,
                  float* __restrict__ tauacc, int q, int p, int use_store) {
    __shared__ __align__(16) float Dp[ROWS_P][12];      // 64 rows x 48 B = 3 KB
    int j  = blockIdx.x * TPB + threadIdx.x;
    int i0 = blockIdx.y * ROWS_P;
    for (int t = threadIdx.x; t < ROWS_P * RNK; t += TPB) {
        int row = t / RNK, k = t - row * RNK;
        Dp[row][k] = Drow[(size_t)i0 * RNK + t];
    }
    __syncthreads();
    f2 b2[5];
    #pragma unroll
    for (int k = 0; k < 5; ++k)
        b2[k] = (f2){Bm[(2*k)*q + j], Bm[(2*k+1)*q + j]};
    float csg = (*cptr) * (use_store ? sigstore[j] : *sigma0p);
    float a0 = 0.0f;
    float y[8];
    #pragma unroll
    for (int u = 0; u < 8; ++u) y[u] = Y[(size_t)(i0+u)*q + j];
    for (int g = 0; g < ROWS_P; g += 8) {
        float yn[8];
        if (g + 8 < ROWS_P) {
            #pragma unroll
            for (int u = 0; u < 8; ++u) yn[u] = Y[(size_t)(i0+g+8+u)*q + j];
        } else {
            #pragma unroll
            for (int u = 0; u < 8; ++u) yn[u] = 0.0f;
        }
        #pragma unroll
        for (int u = 0; u < 8; ++u) {
            int rl = g + u;                   // block-local row
            f2 dot2 = {0.0f, 0.0f};
            #pragma unroll
            for (int k = 0; k < 5; ++k) {
                f2 d2 = *(const f2*)&Dp[rl][2*k];
                dot2 = __builtin_elementwise_fma(d2, b2[k], dot2);
            }
            float dot = dot2[0] + dot2[1];
            float r = (y[u] != 0.0f) ? y[u] - dot : 0.0f;
            r = fminf(fmaxf(r, -csg), csg);
            a0 = fmaf(r, r, a0);
        }
        #pragma unroll
        for (int u = 0; u < 8; ++u) y[u] = yn[u];
    }
    atomicAdd(&tauacc[j], a0);
}

// pass2: sigma_new inline from tauacc; rhs[k][j] += D[i,k]*clamp(resid,+-c*sigma_new).
// Same LDS-D + pk_fma structure; rhs accumulate also packed (5 pk_fma).
__global__ __launch_bounds__(TPB)
void pass2_kernel(const float* __restrict__ Y, const float* __restrict__ Drow,
                  const float* __restrict__ Bm, const float* __restrict__ Gbuf,
                  const float* __restrict__ tauacc, float* __restrict__ sigstore,
                  const float* __restrict__ cptr, const float* __restrict__ alphap,
                  const float* __restrict__ lamdap, const float* __restrict__ sigma0p,
                  float* __restrict__ rhs, int q, int p, int mode) {
    __shared__ __align__(16) float Dp[ROWS_P][12];
    int j  = blockIdx.x * TPB + threadIdx.x;
    int i0 = blockIdx.y * ROWS_P;
    for (int t = threadIdx.x; t < ROWS_P * RNK; t += TPB) {
        int row = t / RNK, k = t - row * RNK;
        Dp[row][k] = Drow[(size_t)i0 * RNK + t];
    }
    __syncthreads();
    f2 b2[5];
    #pragma unroll
    for (int k = 0; k < 5; ++k)
        b2[k] = (f2){Bm[(2*k)*q + j], Bm[(2*k+1)*q + j]};
    float so  = mode ? sigstore[j] : *sigma0p;
    float nb  = Gbuf[NG*q + j];
    float tau = sqrtf(tauacc[j] / (2.0f * nb * (*alphap))) / so;
    float sg  = so * powf(tau, *lamdap);
    if (mode == 0 && blockIdx.y == 0) sigstore[j] = sg;
    float csg = (*cptr) * sg;

    f2 a2[5];
    #pragma unroll
    for (int k = 0; k < 5; ++k) a2[k] = (f2){0.0f, 0.0f};
    float y[8];
    #pragma unroll
    for (int u = 0; u < 8; ++u) y[u] = Y[(size_t)(i0+u)*q + j];
    for (int g = 0; g < ROWS_P; g += 8) {
        float yn[8];
        if (g + 8 < ROWS_P) {
            #pragma unroll
            for (int u = 0; u < 8; ++u) yn[u] = Y[(size_t)(i0+g+8+u)*q + j];
        } else {
            #pragma unroll
            for (int u = 0; u < 8; ++u) yn[u] = 0.0f;
        }
        #pragma unroll
        for (int u = 0; u < 8; ++u) {
            int rl = g + u;
            f2 d2[5];
            #pragma unroll
            for (int k = 0; k < 5; ++k) d2[k] = *(const f2*)&Dp[rl][2*k];
            f2 dot2 = {0.0f, 0.0f};
            #pragma unroll
            for (int k = 0; k < 5; ++k)
                dot2 = __builtin_elementwise_fma(d2[k], b2[k], dot2);
            float dot = dot2[0] + dot2[1];
            float r = (y[u] != 0.0f) ? y[u] - dot : 0.0f;
            r = fminf(fmaxf(r, -csg), csg);   // psi2 * sigma_new
            f2 rv = {r, r};
            #pragma unroll
            for (int k = 0; k < 5; ++k)
                a2[k] = __builtin_elementwise_fma(d2[k], rv, a2[k]);
        }
        #pragma unroll
        for (int u = 0; u < 8; ++u) y[u] = yn[u];
    }
    #pragma unroll
    for (int k = 0; k < 5; ++k) {
        atomicAdd(&rhs[(2*k)*q   + j], a2[k][0]);
        atomicAdd(&rhs[(2*k+1)*q + j], a2[k][1]);
    }
}

// Cholesky of raw G (in registers) + solve + beta += mu*delta.
// 64-thread blocks + launch_bounds(64): VGPR cap lifted (needs ~85 live) -> no
// scratch spill (round-3 counters: VGPR_Count=64 + 96us _ord-0 scratch setup).
__global__ __launch_bounds__(TPBU)
void update_kernel(float* __restrict__ Gbuf, float* __restrict__ rhs,
                   float* __restrict__ Bm, float* __restrict__ Brow,
                   const float* __restrict__ mup,
                   float* __restrict__ tauacc, int q, int zero_g) {
    int j = blockIdx.x * TPBU + threadIdx.x;
    if (j >= q) return;
    float g[NG];
    #pragma unroll
    for (int k = 0; k < NG; ++k) g[k] = Gbuf[k*q + j];
    #pragma unroll
    for (int a = 0; a < RNK; ++a) {          // in-register Cholesky
        #pragma unroll
        for (int b = 0; b < a; ++b) {
            float s = g[tri(a,b)];
            #pragma unroll
            for (int k = 0; k < b; ++k) s -= g[tri(a,k)] * g[tri(b,k)];
            g[tri(a,b)] = s / g[tri(b,b)];
        }
        float s = g[tri(a,a)];
        #pragma unroll
        for (int k = 0; k < a; ++k) s -= g[tri(a,k)] * g[tri(a,k)];
        g[tri(a,a)] = sqrtf(s);
    }
    float x[RNK];
    #pragma unroll
    for (int k = 0; k < RNK; ++k) x[k] = rhs[k*q + j];
    #pragma unroll
    for (int a = 0; a < RNK; ++a) {          // forward: L y = rhs
        float s = x[a];
        #pragma unroll
        for (int k = 0; k < a; ++k) s -= g[tri(a,k)] * x[k];
        x[a] = s / g[tri(a,a)];
    }
    #pragma unroll
    for (int a = RNK-1; a >= 0; --a) {       // backward: L^T d = y
        float s = x[a];
        #pragma unroll
        for (int k = a+1; k < RNK; ++k) s -= g[tri(k,a)] * x[k];
        x[a] = s / g[tri(a,a)];
    }
    float mu = *mup;
    #pragma unroll
    for (int k = 0; k < RNK; ++k) {
        float nb = Bm[k*q + j] + mu * x[k];
        Bm[k*q + j] = nb;
        Brow[(size_t)j*RNK + k] = nb;
    }
    tauacc[j] = 0.0f;
    #pragma unroll
    for (int k = 0; k < RNK; ++k) rhs[k*q + j] = 0.0f;
    if (zero_g) {
        #pragma unroll
        for (int k = 0; k <= NG; ++k) Gbuf[k*q + j] = 0.0f;
    }
}

// final: out[i*n+j] = sum_k Ut[k*m+i] * Vc[k*n+j]
__global__ void gemm_kernel(const float* __restrict__ Ut, const float* __restrict__ Vc,
                            float* __restrict__ out, int m, int n) {
    int j  = blockIdx.x * TPB + threadIdx.x;
    int i0 = blockIdx.y * ITILE;
    float v[RNK];
    #pragma unroll
    for (int k = 0; k < RNK; ++k) v[k] = Vc[k*n + j];
    for (int i = i0; i < i0 + ITILE; ++i) {
        float acc = 0.0f;
        #pragma unroll
        for (int k = 0; k < RNK; ++k) acc = fmaf(Ut[k*m + i], v[k], acc);
        out[(size_t)i*n + j] = acc;
    }
}

// ---------------- host side ----------------

namespace {
struct Scratch {
    float *Ut, *Vc, *Urow, *Vrow, *Gbuf, *rhs, *sigma, *tauacc, *alpha;
    unsigned *maskV, *maskU;
};

static void hubreg(const float* Y, const unsigned* mask, const float* Drow,
                   float* Bm, float* Brow, int q, int p,
                   const float* c, const float* lamda, const float* mu, const float* sigma0,
                   const Scratch& s, hipStream_t stream) {
    dim3 gg(q / TPB, p / (32 * WPC));    // gram: 512 blocks
    dim3 gp(q / TPB, p / ROWS_P);        // pass kernels: (16,64) = 1024 blocks
    dim3 gj(q / TPBU);                   // update: 64 blocks of 1 wave

    gram_kernel  <<<gg, TPB, 0, stream>>>(mask, Drow, s.Gbuf, q, p);
    pass1_kernel <<<gp, TPB, 0, stream>>>(Y, Drow, Bm, s.sigma, sigma0, c, s.tauacc, q, p, 0);
    pass2_kernel <<<gp, TPB, 0, stream>>>(Y, Drow, Bm, s.Gbuf, s.tauacc, s.sigma, c,
                                          s.alpha, lamda, sigma0, s.rhs, q, p, 0);
    update_kernel<<<gj, TPBU, 0, stream>>>(s.Gbuf, s.rhs, Bm, Brow, mu, s.tauacc, q, 0);
    pass1_kernel <<<gp, TPB, 0, stream>>>(Y, Drow, Bm, s.sigma, sigma0, c, s.tauacc, q, p, 1);
    pass2_kernel <<<gp, TPB, 0, stream>>>(Y, Drow, Bm, s.Gbuf, s.tauacc, s.sigma, c,
                                          s.alpha, lamda, sigma0, s.rhs, q, p, 1);
    update_kernel<<<gj, TPBU, 0, stream>>>(s.Gbuf, s.rhs, Bm, Brow, mu, s.tauacc, q, 1);
}
} // namespace

extern "C" void kernel_launch(void* const* d_in, const int* in_sizes, int n_in,
                              void* d_out, int out_size, void* d_ws, size_t ws_size,
                              hipStream_t stream) {
    const float* Uin    = (const float*)d_in[0];
    const float* Vin    = (const float*)d_in[1];
    const float* X      = (const float*)d_in[2];
    const float* c      = (const float*)d_in[3];
    const float* lamda  = (const float*)d_in[4];
    const float* mu     = (const float*)d_in[5];
    const float* sigma0 = (const float*)d_in[6];
    float* out = (float*)d_out;

    const int m = in_sizes[0] / RNK;   // 4096
    const int n = in_sizes[1] / RNK;   // 4096
    const int qmax = (m > n) ? m : n;

    float* w = (float*)d_ws;
    auto align64 = [](size_t x) { return (x + 63) & ~(size_t)63; };
    size_t off = 0;
    Scratch s;
    s.Ut     = w + off; off = align64(off + (size_t)RNK * m);
    s.Vc     = w + off; off = align64(off + (size_t)RNK * n);
    s.Urow   = w + off; off = align64(off + (size_t)RNK * m);
    s.Vrow   = w + off; off = align64(off + (size_t)RNK * n);
    s.Gbuf   = w + off; off = align64(off + (size_t)(NG + 1) * qmax);
    s.rhs    = w + off; off = align64(off + (size_t)RNK * qmax);
    s.sigma  = w + off; off = align64(off + (size_t)qmax);
    s.tauacc = w + off; off = align64(off + (size_t)qmax);
    s.alpha  = w + off; off = align64(off + 64);
    s.maskV  = (unsigned*)(w + off); off = align64(off + (size_t)(m/32) * n);
    s.maskU  = (unsigned*)(w + off); off = align64(off + (size_t)(n/32) * m);
    (void)ws_size; (void)n_in; (void)out_size;

    {
        int tot = (NG + 1) * qmax;
        init_kernel<<<(tot + TPB - 1) / TPB, TPB, 0, stream>>>(
            Uin, Vin, c, s.Ut, s.Vc, s.Urow, s.Vrow, s.Gbuf, s.tauacc, s.rhs,
            s.alpha, m, n, qmax);
    }
    // X [m,n] -> XT [n,m] staged in d_out (dead until final GEMM overwrites it)
    transpose_kernel<<<dim3(n / 32, m / 32), dim3(32, 8), 0, stream>>>(X, out, m, n);
    mask_kernel<<<dim3(n / 256, m / 32), TPB, 0, stream>>>(X, s.maskV, s.maskU, m, n);

    for (int layer = 0; layer < 3; ++layer) {
        // V-step: q=n regressions (cols of X), D rows = U rows (Urow), beta = V cols
        hubreg(X,   s.maskV, s.Urow, s.Vc, s.Vrow, n, m, c, lamda, mu, sigma0, s, stream);
        // U-step: q=m regressions (rows of X), Y = XT, D rows = V cols (Vrow), beta = U rows
        hubreg(out, s.maskU, s.Vrow, s.Ut, s.Urow, m, n, c, lamda, mu, sigma0, s, stream);
    }

    gemm_kernel<<<dim3(n / TPB, m / ITILE), TPB, 0, stream>>>(s.Ut, s.Vc, out, m, n);
}